// Round 5
// baseline (497.403 us; speedup 1.0000x reference)
//
#include <hip/hip_runtime.h>

// PMField R5: R4 dataflow (verified) + occupancy & barrier fixes.
//  - 512-thread blocks (8 waves) -> 2 waves/SIMD at 108 KB LDS (1 block/CU).
//  - NO in-loop __syncthreads: w/z scratch is wave-private; intra-wave LDS
//    ordering is lgkmcnt (compiler). R4 paid ~40 CU-wide barriers/block.
//  - single wave-private buffer [32][72] bf16 (z-bf16 then w, time-shared).
//  - fp32 z staging overlaid on the center region (dead at that point).
//  - w packs truncate (1 op) instead of round-half-up (3 ops); z/centers
//    keep rounding (dot accuracy).
// Layouts (HW-verified): C/D col=lane&15,row=q*4+r; A[m=lane&15][k=q*8+j];
// B = transpose-dual.

#define STEPS 8
#define DTB   0.15f
#define EPSF  1e-4f

typedef short bf16x8 __attribute__((ext_vector_type(8)));
typedef float f32x4  __attribute__((ext_vector_type(4)));
union FragU { int4 i; bf16x8 h; };

__device__ __forceinline__ unsigned bf1(float a) {           // round-half-up
    return (__float_as_uint(a) + 0x8000u) >> 16;
}
__device__ __forceinline__ unsigned bfp(float lo, float hi) { // round pack
    return ((__float_as_uint(lo) + 0x8000u) >> 16) |
           ((__float_as_uint(hi) + 0x8000u) & 0xFFFF0000u);
}
__device__ __forceinline__ unsigned bfpt(float lo, float hi) { // trunc pack
    return (__float_as_uint(lo) >> 16) | (__float_as_uint(hi) & 0xFFFF0000u);
}
__device__ __forceinline__ float up_hi(unsigned u) { return __uint_as_float(u & 0xFFFF0000u); }
__device__ __forceinline__ float up_lo(unsigned u) { return __uint_as_float(u << 16); }
__device__ __forceinline__ float med3(float x, float lo, float hi) {
    return __builtin_amdgcn_fmed3f(x, lo, hi);
}

__global__ __launch_bounds__(512, 2)
void pmfield_kernel(const float* __restrict__ z_in,
                    const float* __restrict__ centers,
                    const float* __restrict__ mus,
                    float* __restrict__ z_out) {
    // sMem: sCS [256][72] bf16 (-2c) then sCT [64][264] bf16 (c).
    // Prologue/epilogue: same bytes reused as fp32 z staging [8 waves][32][68].
    __shared__ __align__(16) unsigned short sMem[256 * 72 + 64 * 264];
    __shared__ unsigned sC2M[256];                       // hi=bf16(cn2) lo=bf16(mu)
    __shared__ __align__(16) unsigned short sWB[8 * 32 * 72];  // wave-private

    unsigned short* sCS  = sMem;                 // row stride 72 shorts
    unsigned short* sCT  = sMem + 256 * 72;      // row stride 264 shorts
    unsigned*       sCSu = (unsigned*)sCS;       // row stride 36 uints
    unsigned*       sCTu = (unsigned*)sCT;       // row stride 132 uints
    float*          fstage = (float*)sMem;       // [wave][32][68] fp32

    const int tid  = threadIdx.x;
    const int lane = tid & 63;
    const int w    = tid >> 6;                   // wave 0..7
    const int m16  = lane & 15;
    const int q    = lane >> 4;

    const int pbase = blockIdx.x * 256;          // 256 particles/block

    // ---- stage z fp32 -> fstage (coalesced), per-wave regions ----
    {
        const f32x4* zg = (const f32x4*)(z_in + (size_t)pbase * 64);
#pragma unroll
        for (int k = 0; k < 8; ++k) {
            int idx = k * 512 + tid;
            int p = idx >> 4, c4 = idx & 15;
            *(f32x4*)(fstage + (p >> 5) * 2176 + (p & 31) * 68 + c4 * 4) = zg[idx];
        }
    }
    __syncthreads();

    // ---- z into C/D-layout regs: rows=dims cols=particles ----
    float* fwz = fstage + w * 2176;
    f32x4 z[4][2];
#pragma unroll
    for (int Mt = 0; Mt < 4; ++Mt)
#pragma unroll
        for (int Nt = 0; Nt < 2; ++Nt)
            z[Mt][Nt] = *(const f32x4*)(fwz + (m16 + 16 * Nt) * 68 + 16 * Mt + 4 * q);
    __syncthreads();   // staging region dead; becomes centers

    // ---- stage centers (both orientations) + cn2/mu; thread pair per center ----
    {
        const int cidx = tid >> 1;               // center 0..255
        const int half = tid & 1;                // 8 f32x4 each
        const f32x4* cg = (const f32x4*)(centers + cidx * 64);
        float c2 = 0.f;
#pragma unroll
        for (int ii = 0; ii < 8; ++ii) {
            int i = half * 8 + ii;
            f32x4 v = cg[i];
            c2 = fmaf(v[0], v[0], fmaf(v[1], v[1], fmaf(v[2], v[2], fmaf(v[3], v[3], c2))));
            sCSu[cidx * 36 + 2 * i]     = bfp(-2.f * v[0], -2.f * v[1]);
            sCSu[cidx * 36 + 2 * i + 1] = bfp(-2.f * v[2], -2.f * v[3]);
            sCT[(4 * i + 0) * 264 + cidx] = (unsigned short)bf1(v[0]);
            sCT[(4 * i + 1) * 264 + cidx] = (unsigned short)bf1(v[1]);
            sCT[(4 * i + 2) * 264 + cidx] = (unsigned short)bf1(v[2]);
            sCT[(4 * i + 3) * 264 + cidx] = (unsigned short)bf1(v[3]);
        }
        c2 += __shfl_xor(c2, 1, 64);
        sC2M[cidx] = ((__float_as_uint(c2) + 0x8000u) & 0xFFFF0000u) | bf1(mus[cidx]);
    }
    __syncthreads();

    unsigned* wbu = (unsigned*)(sWB + w * 2304);   // wave-private [32][36] uints

#pragma unroll 1
    for (int s = 0; s < STEPS; ++s) {
        // zz per particle
        float zzp[2];
#pragma unroll
        for (int Nt = 0; Nt < 2; ++Nt) {
            float a = 0.f;
#pragma unroll
            for (int Mt = 0; Mt < 4; ++Mt)
#pragma unroll
                for (int r = 0; r < 4; ++r) a = fmaf(z[Mt][Nt][r], z[Mt][Nt][r], a);
            a += __shfl_xor(a, 16, 64);
            a += __shfl_xor(a, 32, 64);
            zzp[Nt] = a;
        }

        // z (bf16, rounded) -> wave buffer [particle][dim]
#pragma unroll
        for (int Mt = 0; Mt < 4; ++Mt)
#pragma unroll
            for (int Nt = 0; Nt < 2; ++Nt) {
                int p = m16 + 16 * Nt;
                unsigned u0 = bfp(z[Mt][Nt][0], z[Mt][Nt][1]);
                unsigned u1 = bfp(z[Mt][Nt][2], z[Mt][Nt][3]);
                *(uint2*)(wbu + p * 36 + 8 * Mt + 2 * q) = make_uint2(u0, u1);
            }
        // wave-private: no barrier, lgkmcnt orders write->read

        FragU zf[2][2];
#pragma unroll
        for (int Kt = 0; Kt < 2; ++Kt)
#pragma unroll
            for (int Nt = 0; Nt < 2; ++Nt) {
                int p = m16 + 16 * Nt;
                zf[Kt][Nt].i = *(const int4*)(wbu + p * 36 + 16 * Kt + 4 * q);
            }

        f32x4 g[4][2];
#pragma unroll
        for (int Mt = 0; Mt < 4; ++Mt)
#pragma unroll
            for (int Nt = 0; Nt < 2; ++Nt) g[Mt][Nt] = (f32x4){0.f, 0.f, 0.f, 0.f};
        float nacc[2] = {0.f, 0.f}, swp[2] = {0.f, 0.f};

#pragma unroll
        for (int c = 0; c < 4; ++c) {            // 4 chunks x 64 centers
            // S^T chunk: rows=centers, cols=particles
            f32x4 S[4][2];
#pragma unroll
            for (int Mt = 0; Mt < 4; ++Mt) {
                int cm = 16 * (4 * c + Mt) + m16;
                FragU a0, a1;
                a0.i = *(const int4*)(sCSu + cm * 36 + 4 * q);
                a1.i = *(const int4*)(sCSu + cm * 36 + 16 + 4 * q);
#pragma unroll
                for (int Nt = 0; Nt < 2; ++Nt) {
                    f32x4 acc = (f32x4){0.f, 0.f, 0.f, 0.f};
                    acc = __builtin_amdgcn_mfma_f32_16x16x32_bf16(a0.h, zf[0][Nt].h, acc, 0, 0, 0);
                    acc = __builtin_amdgcn_mfma_f32_16x16x32_bf16(a1.h, zf[1][Nt].h, acc, 0, 0, 0);
                    S[Mt][Nt] = acc;
                }
            }

            // elementwise: r2 -> w (bf16 trunc into wave buffer), n/sw partials
#pragma unroll
            for (int Mt = 0; Mt < 4; ++Mt) {
                uint4 cmv = *(const uint4*)(sC2M + 16 * (4 * c + Mt) + 4 * q);
                float wv[2][4];
#pragma unroll
                for (int r = 0; r < 4; ++r) {
                    unsigned cu = (r == 0) ? cmv.x : (r == 1) ? cmv.y : (r == 2) ? cmv.z : cmv.w;
                    float cn2 = up_hi(cu), mu = up_lo(cu);
#pragma unroll
                    for (int Nt = 0; Nt < 2; ++Nt) {
                        float r2  = fmaxf(S[Mt][Nt][r] + zzp[Nt] + cn2, 0.f) + EPSF;
                        float rin = __builtin_amdgcn_rsqf(r2);
                        float mur = mu * rin;
                        nacc[Nt] += mur;
                        float wval = mur * rin * rin;   // mu / r^3
                        swp[Nt] += wval;
                        wv[Nt][r] = wval;
                    }
                }
#pragma unroll
                for (int Nt = 0; Nt < 2; ++Nt) {
                    int p = m16 + 16 * Nt;
                    unsigned u0 = bfpt(wv[Nt][0], wv[Nt][1]);
                    unsigned u1 = bfpt(wv[Nt][2], wv[Nt][3]);
                    *(uint2*)(wbu + p * 36 + 8 * Mt + 2 * q) = make_uint2(u0, u1);
                }
            }
            // wave-private: no barrier

            // G^T += C^T(chunk) @ W^T(chunk)
            FragU wf[2][2];
#pragma unroll
            for (int Kt = 0; Kt < 2; ++Kt)
#pragma unroll
                for (int Nt = 0; Nt < 2; ++Nt) {
                    int p = m16 + 16 * Nt;
                    wf[Kt][Nt].i = *(const int4*)(wbu + p * 36 + 16 * Kt + 4 * q);
                }
#pragma unroll
            for (int Mt = 0; Mt < 4; ++Mt) {
                int dm = 16 * Mt + m16;
                FragU ga0, ga1;
                ga0.i = *(const int4*)(sCTu + dm * 132 + 32 * c + 4 * q);
                ga1.i = *(const int4*)(sCTu + dm * 132 + 32 * c + 16 + 4 * q);
#pragma unroll
                for (int Nt = 0; Nt < 2; ++Nt) {
                    g[Mt][Nt] = __builtin_amdgcn_mfma_f32_16x16x32_bf16(ga0.h, wf[0][Nt].h, g[Mt][Nt], 0, 0, 0);
                    g[Mt][Nt] = __builtin_amdgcn_mfma_f32_16x16x32_bf16(ga1.h, wf[1][Nt].h, g[Mt][Nt], 0, 0, 0);
                }
            }
        }

        // reduce n, sw; update z
        float tco[2], swf[2];
#pragma unroll
        for (int Nt = 0; Nt < 2; ++Nt) {
            float a = nacc[Nt];
            a += __shfl_xor(a, 16, 64);
            a += __shfl_xor(a, 32, 64);
            float b = swp[Nt];
            b += __shfl_xor(b, 16, 64);
            b += __shfl_xor(b, 32, 64);
            tco[Nt] = DTB * __builtin_amdgcn_rcpf(1.f + a);
            swf[Nt] = b;
        }
#pragma unroll
        for (int Mt = 0; Mt < 4; ++Mt)
#pragma unroll
            for (int Nt = 0; Nt < 2; ++Nt)
#pragma unroll
                for (int r = 0; r < 4; ++r) {
                    float gd = fmaf(-swf[Nt], z[Mt][Nt][r], g[Mt][Nt][r]);
                    z[Mt][Nt][r] = med3(fmaf(tco[Nt], gd, z[Mt][Nt][r]), -3.f, 3.f);
                }
    }

    // ---- epilogue: all waves done with centers, then fp32 transpose out ----
    __syncthreads();
#pragma unroll
    for (int Mt = 0; Mt < 4; ++Mt)
#pragma unroll
        for (int Nt = 0; Nt < 2; ++Nt)
            *(f32x4*)(fwz + (m16 + 16 * Nt) * 68 + 16 * Mt + 4 * q) = z[Mt][Nt];
    // own-wave region only: no barrier needed
    {
        float* outb = z_out + (size_t)(pbase + 32 * w) * 64;
#pragma unroll
        for (int k = 0; k < 8; ++k) {
            int flat = k * 64 + lane;
            int row = flat >> 4, c4 = flat & 15;
            f32x4 v = *(const f32x4*)(fwz + row * 68 + c4 * 4);
            *(f32x4*)(outb + row * 64 + c4 * 4) = v;
        }
    }
}

extern "C" void kernel_launch(void* const* d_in, const int* in_sizes, int n_in,
                              void* d_out, int out_size, void* d_ws, size_t ws_size,
                              hipStream_t stream) {
    const float* z       = (const float*)d_in[0];
    const float* centers = (const float*)d_in[1];
    const float* mus     = (const float*)d_in[2];
    float* out           = (float*)d_out;

    // 131072 particles / 256 per block (8 waves x 32) = 512 blocks
    pmfield_kernel<<<dim3(512), dim3(512), 0, stream>>>(z, centers, mus, out);
}

// Round 6
// 462.569 us; speedup vs baseline: 1.0753x; 1.0753x over previous
//
#include <hip/hip_runtime.h>

// PMField R6: R5 structure + spill fix.
//  - amdgpu_waves_per_eu(2,2): pins exactly 2 waves/EU -> 256-VGPR budget and
//    disables the allocator's "shrink to 128 for more waves" heuristic that
//    caused R5's 1.1 GB of spill FETCH traffic.
//  - S-phase fused per Mt: compute S[Mt] (8 regs), elementwise, write w,
//    drop it -- instead of materializing S[4][2] (32 regs). Peak live ~150.
//  - 512-thread blocks (8 waves), wave-private scratch, no in-loop barriers.
// Layouts (HW-verified): C/D col=lane&15,row=q*4+r; A[m=lane&15][k=q*8+j];
// B = transpose-dual.

#define STEPS 8
#define DTB   0.15f
#define EPSF  1e-4f

typedef short bf16x8 __attribute__((ext_vector_type(8)));
typedef float f32x4  __attribute__((ext_vector_type(4)));
union FragU { int4 i; bf16x8 h; };

__device__ __forceinline__ unsigned bf1(float a) {           // round-half-up
    return (__float_as_uint(a) + 0x8000u) >> 16;
}
__device__ __forceinline__ unsigned bfp(float lo, float hi) { // round pack
    return ((__float_as_uint(lo) + 0x8000u) >> 16) |
           ((__float_as_uint(hi) + 0x8000u) & 0xFFFF0000u);
}
__device__ __forceinline__ unsigned bfpt(float lo, float hi) { // trunc pack
    return (__float_as_uint(lo) >> 16) | (__float_as_uint(hi) & 0xFFFF0000u);
}
__device__ __forceinline__ float up_hi(unsigned u) { return __uint_as_float(u & 0xFFFF0000u); }
__device__ __forceinline__ float up_lo(unsigned u) { return __uint_as_float(u << 16); }
__device__ __forceinline__ float med3(float x, float lo, float hi) {
    return __builtin_amdgcn_fmed3f(x, lo, hi);
}

__global__ __launch_bounds__(512)
__attribute__((amdgpu_waves_per_eu(2, 2)))
void pmfield_kernel(const float* __restrict__ z_in,
                    const float* __restrict__ centers,
                    const float* __restrict__ mus,
                    float* __restrict__ z_out) {
    // sMem: sCS [256][72] bf16 (-2c) then sCT [64][264] bf16 (c).
    // Prologue/epilogue: same bytes reused as fp32 z staging [8 waves][32][68].
    __shared__ __align__(16) unsigned short sMem[256 * 72 + 64 * 264];
    __shared__ unsigned sC2M[256];                       // hi=bf16(cn2) lo=bf16(mu)
    __shared__ __align__(16) unsigned short sWB[8 * 32 * 72];  // wave-private

    unsigned short* sCT  = sMem + 256 * 72;      // row stride 264 shorts
    unsigned*       sCSu = (unsigned*)sMem;      // row stride 36 uints
    unsigned*       sCTu = (unsigned*)sCT;       // row stride 132 uints
    float*          fstage = (float*)sMem;       // [wave][32][68] fp32

    const int tid  = threadIdx.x;
    const int lane = tid & 63;
    const int w    = tid >> 6;                   // wave 0..7
    const int m16  = lane & 15;
    const int q    = lane >> 4;

    const int pbase = blockIdx.x * 256;          // 256 particles/block

    // ---- stage z fp32 -> fstage (coalesced), per-wave regions ----
    {
        const f32x4* zg = (const f32x4*)(z_in + (size_t)pbase * 64);
#pragma unroll
        for (int k = 0; k < 8; ++k) {
            int idx = k * 512 + tid;
            int p = idx >> 4, c4 = idx & 15;
            *(f32x4*)(fstage + (p >> 5) * 2176 + (p & 31) * 68 + c4 * 4) = zg[idx];
        }
    }
    __syncthreads();

    // ---- z into C/D-layout regs: rows=dims cols=particles ----
    float* fwz = fstage + w * 2176;
    f32x4 z[4][2];
#pragma unroll
    for (int Mt = 0; Mt < 4; ++Mt)
#pragma unroll
        for (int Nt = 0; Nt < 2; ++Nt)
            z[Mt][Nt] = *(const f32x4*)(fwz + (m16 + 16 * Nt) * 68 + 16 * Mt + 4 * q);
    __syncthreads();   // staging region dead; becomes centers

    // ---- stage centers (both orientations) + cn2/mu; thread pair per center ----
    {
        const int cidx = tid >> 1;               // center 0..255
        const int half = tid & 1;                // 8 f32x4 each
        const f32x4* cg = (const f32x4*)(centers + cidx * 64);
        float c2 = 0.f;
#pragma unroll
        for (int ii = 0; ii < 8; ++ii) {
            int i = half * 8 + ii;
            f32x4 v = cg[i];
            c2 = fmaf(v[0], v[0], fmaf(v[1], v[1], fmaf(v[2], v[2], fmaf(v[3], v[3], c2))));
            sCSu[cidx * 36 + 2 * i]     = bfp(-2.f * v[0], -2.f * v[1]);
            sCSu[cidx * 36 + 2 * i + 1] = bfp(-2.f * v[2], -2.f * v[3]);
            sCT[(4 * i + 0) * 264 + cidx] = (unsigned short)bf1(v[0]);
            sCT[(4 * i + 1) * 264 + cidx] = (unsigned short)bf1(v[1]);
            sCT[(4 * i + 2) * 264 + cidx] = (unsigned short)bf1(v[2]);
            sCT[(4 * i + 3) * 264 + cidx] = (unsigned short)bf1(v[3]);
        }
        c2 += __shfl_xor(c2, 1, 64);
        sC2M[cidx] = ((__float_as_uint(c2) + 0x8000u) & 0xFFFF0000u) | bf1(mus[cidx]);
    }
    __syncthreads();

    unsigned* wbu = (unsigned*)(sWB + w * 2304);   // wave-private [32][36] uints

#pragma unroll 1
    for (int s = 0; s < STEPS; ++s) {
        // zz per particle
        float zzp[2];
#pragma unroll
        for (int Nt = 0; Nt < 2; ++Nt) {
            float a = 0.f;
#pragma unroll
            for (int Mt = 0; Mt < 4; ++Mt)
#pragma unroll
                for (int r = 0; r < 4; ++r) a = fmaf(z[Mt][Nt][r], z[Mt][Nt][r], a);
            a += __shfl_xor(a, 16, 64);
            a += __shfl_xor(a, 32, 64);
            zzp[Nt] = a;
        }

        // z (bf16, rounded) -> wave buffer [particle][dim]
#pragma unroll
        for (int Mt = 0; Mt < 4; ++Mt)
#pragma unroll
            for (int Nt = 0; Nt < 2; ++Nt) {
                int p = m16 + 16 * Nt;
                unsigned u0 = bfp(z[Mt][Nt][0], z[Mt][Nt][1]);
                unsigned u1 = bfp(z[Mt][Nt][2], z[Mt][Nt][3]);
                *(uint2*)(wbu + p * 36 + 8 * Mt + 2 * q) = make_uint2(u0, u1);
            }
        // wave-private: no barrier, lgkmcnt orders write->read

        FragU zf[2][2];
#pragma unroll
        for (int Kt = 0; Kt < 2; ++Kt)
#pragma unroll
            for (int Nt = 0; Nt < 2; ++Nt) {
                int p = m16 + 16 * Nt;
                zf[Kt][Nt].i = *(const int4*)(wbu + p * 36 + 16 * Kt + 4 * q);
            }

        f32x4 g[4][2];
#pragma unroll
        for (int Mt = 0; Mt < 4; ++Mt)
#pragma unroll
            for (int Nt = 0; Nt < 2; ++Nt) g[Mt][Nt] = (f32x4){0.f, 0.f, 0.f, 0.f};
        float nacc[2] = {0.f, 0.f}, swp[2] = {0.f, 0.f};

#pragma unroll
        for (int c = 0; c < 4; ++c) {            // 4 chunks x 64 centers
            // Fused S-phase: one Mt at a time (8 live S regs, not 32)
#pragma unroll
            for (int Mt = 0; Mt < 4; ++Mt) {
                int cm = 16 * (4 * c + Mt) + m16;
                FragU a0, a1;
                a0.i = *(const int4*)(sCSu + cm * 36 + 4 * q);
                a1.i = *(const int4*)(sCSu + cm * 36 + 16 + 4 * q);
                f32x4 S[2];
#pragma unroll
                for (int Nt = 0; Nt < 2; ++Nt) {
                    f32x4 acc = (f32x4){0.f, 0.f, 0.f, 0.f};
                    acc = __builtin_amdgcn_mfma_f32_16x16x32_bf16(a0.h, zf[0][Nt].h, acc, 0, 0, 0);
                    acc = __builtin_amdgcn_mfma_f32_16x16x32_bf16(a1.h, zf[1][Nt].h, acc, 0, 0, 0);
                    S[Nt] = acc;
                }

                uint4 cmv = *(const uint4*)(sC2M + 16 * (4 * c + Mt) + 4 * q);
                float wv[2][4];
#pragma unroll
                for (int r = 0; r < 4; ++r) {
                    unsigned cu = (r == 0) ? cmv.x : (r == 1) ? cmv.y : (r == 2) ? cmv.z : cmv.w;
                    float cn2 = up_hi(cu), mu = up_lo(cu);
#pragma unroll
                    for (int Nt = 0; Nt < 2; ++Nt) {
                        float r2  = fmaxf(S[Nt][r] + zzp[Nt] + cn2, 0.f) + EPSF;
                        float rin = __builtin_amdgcn_rsqf(r2);
                        float mur = mu * rin;
                        nacc[Nt] += mur;
                        float wval = mur * rin * rin;   // mu / r^3
                        swp[Nt] += wval;
                        wv[Nt][r] = wval;
                    }
                }
#pragma unroll
                for (int Nt = 0; Nt < 2; ++Nt) {
                    int p = m16 + 16 * Nt;
                    unsigned u0 = bfpt(wv[Nt][0], wv[Nt][1]);
                    unsigned u1 = bfpt(wv[Nt][2], wv[Nt][3]);
                    *(uint2*)(wbu + p * 36 + 8 * Mt + 2 * q) = make_uint2(u0, u1);
                }
            }
            // wave-private: no barrier

            // G^T += C^T(chunk) @ W^T(chunk)
            FragU wf[2][2];
#pragma unroll
            for (int Kt = 0; Kt < 2; ++Kt)
#pragma unroll
                for (int Nt = 0; Nt < 2; ++Nt) {
                    int p = m16 + 16 * Nt;
                    wf[Kt][Nt].i = *(const int4*)(wbu + p * 36 + 16 * Kt + 4 * q);
                }
#pragma unroll
            for (int Mt = 0; Mt < 4; ++Mt) {
                int dm = 16 * Mt + m16;
                FragU ga0, ga1;
                ga0.i = *(const int4*)(sCTu + dm * 132 + 32 * c + 4 * q);
                ga1.i = *(const int4*)(sCTu + dm * 132 + 32 * c + 16 + 4 * q);
#pragma unroll
                for (int Nt = 0; Nt < 2; ++Nt) {
                    g[Mt][Nt] = __builtin_amdgcn_mfma_f32_16x16x32_bf16(ga0.h, wf[0][Nt].h, g[Mt][Nt], 0, 0, 0);
                    g[Mt][Nt] = __builtin_amdgcn_mfma_f32_16x16x32_bf16(ga1.h, wf[1][Nt].h, g[Mt][Nt], 0, 0, 0);
                }
            }
        }

        // reduce n, sw; update z
        float tco[2], swf[2];
#pragma unroll
        for (int Nt = 0; Nt < 2; ++Nt) {
            float a = nacc[Nt];
            a += __shfl_xor(a, 16, 64);
            a += __shfl_xor(a, 32, 64);
            float b = swp[Nt];
            b += __shfl_xor(b, 16, 64);
            b += __shfl_xor(b, 32, 64);
            tco[Nt] = DTB * __builtin_amdgcn_rcpf(1.f + a);
            swf[Nt] = b;
        }
#pragma unroll
        for (int Mt = 0; Mt < 4; ++Mt)
#pragma unroll
            for (int Nt = 0; Nt < 2; ++Nt)
#pragma unroll
                for (int r = 0; r < 4; ++r) {
                    float gd = fmaf(-swf[Nt], z[Mt][Nt][r], g[Mt][Nt][r]);
                    z[Mt][Nt][r] = med3(fmaf(tco[Nt], gd, z[Mt][Nt][r]), -3.f, 3.f);
                }
    }

    // ---- epilogue: all waves done with centers, then fp32 transpose out ----
    __syncthreads();
#pragma unroll
    for (int Mt = 0; Mt < 4; ++Mt)
#pragma unroll
        for (int Nt = 0; Nt < 2; ++Nt)
            *(f32x4*)(fwz + (m16 + 16 * Nt) * 68 + 16 * Mt + 4 * q) = z[Mt][Nt];
    // own-wave region only: no barrier needed
    {
        float* outb = z_out + (size_t)(pbase + 32 * w) * 64;
#pragma unroll
        for (int k = 0; k < 8; ++k) {
            int flat = k * 64 + lane;
            int row = flat >> 4, c4 = flat & 15;
            f32x4 v = *(const f32x4*)(fwz + row * 68 + c4 * 4);
            *(f32x4*)(outb + row * 64 + c4 * 4) = v;
        }
    }
}

extern "C" void kernel_launch(void* const* d_in, const int* in_sizes, int n_in,
                              void* d_out, int out_size, void* d_ws, size_t ws_size,
                              hipStream_t stream) {
    const float* z       = (const float*)d_in[0];
    const float* centers = (const float*)d_in[1];
    const float* mus     = (const float*)d_in[2];
    float* out           = (float*)d_out;

    // 131072 particles / 256 per block (8 waves x 32) = 512 blocks
    pmfield_kernel<<<dim3(512), dim3(512), 0, stream>>>(z, centers, mus, out);
}

// Round 7
// 250.455 us; speedup vs baseline: 1.9860x; 1.8469x over previous
//
#include <hip/hip_runtime.h>

// PMField R7: frag-linear center planes precomputed in d_ws by a prep kernel.
//  - Main kernel: 256 thr (4 waves x 32 particles), __launch_bounds__(256,1)
//    -- the only config that empirically avoids the 128-VGPR spill heuristic
//    (R5/R6: 512-thr blocks -> VGPR=128 + 1.07 GB HBM spill traffic).
//  - S-matmul A-frags (-2C) copied d_ws -> LDS once per block (lane-linear,
//    conflict-free b128; R6's [center][dim] layout was 8-way conflicted).
//  - G-matmul A-frags + packed cn2/mu read straight from global (L2-resident).
//  - z state in C/D layout registers; z->B-frag and w->B-frag transposes via
//    wave-private frag-linear LDS planes, explicit scatter mapping:
//      cw=16Mt+4q+r -> plane Kt=Mt>>1, lane m16+16*((2Mt+(q>>1))&3), uint 2(q&1)
//    (wave-internal DS in-order, no barriers -- validated by R5/R6 passing).
//  - LDS total 49,152 B -> 3 blocks/CU if VGPR<=168.
// Layouts (HW-verified): C/D col=lane&15,row=q*4+r; A[m=lane&15][k=q*8+j];
// B = transpose-dual of A.

#define STEPS 8
#define DTB   0.15f
#define EPSF  1e-4f

typedef short bf16x8 __attribute__((ext_vector_type(8)));
typedef float f32x4  __attribute__((ext_vector_type(4)));
union FragU { int4 i; bf16x8 h; };

__device__ __forceinline__ unsigned bf1(float a) {            // round-half-up
    return (__float_as_uint(a) + 0x8000u) >> 16;
}
__device__ __forceinline__ unsigned bfp(float lo, float hi) { // round pack
    return ((__float_as_uint(lo) + 0x8000u) >> 16) |
           ((__float_as_uint(hi) + 0x8000u) & 0xFFFF0000u);
}
__device__ __forceinline__ unsigned bfpt(float lo, float hi) { // trunc pack
    return (__float_as_uint(lo) >> 16) | (__float_as_uint(hi) & 0xFFFF0000u);
}
__device__ __forceinline__ float up_hi(unsigned u) { return __uint_as_float(u & 0xFFFF0000u); }
__device__ __forceinline__ float up_lo(unsigned u) { return __uint_as_float(u << 16); }
__device__ __forceinline__ float med3(float x, float lo, float hi) {
    return __builtin_amdgcn_fmed3f(x, lo, hi);
}

// d_ws layout (int4 units):
//   [0,    2048)  S-planes: ((c*4+Mt)*2+h)*64 + lane   = bf16x8 of -2C[center][dims]
//   [2048, 4096)  G-planes: ((Mt*4+c)*2+h)*64 + lane   = bf16x8 of C^T[dim][centers]
//   [4096, 4160)  cmv: 256 uints, hi=bf16(|c|^2) lo=bf16(mu)
__global__ void pm_prep(const float* __restrict__ centers,
                        const float* __restrict__ mus,
                        unsigned* __restrict__ ws) {
    const int gtid = blockIdx.x * 256 + threadIdx.x;
    if (gtid < 2048) {                       // S-plane frags
        const int c = gtid >> 9, Mt = (gtid >> 7) & 3, h = (gtid >> 6) & 1;
        const int L = gtid & 63, m16 = L & 15, q = L >> 4;
        const float* row = centers + (size_t)(64 * c + 16 * Mt + m16) * 64 + 32 * h + 8 * q;
        uint4 u;
        u.x = bfp(-2.f * row[0], -2.f * row[1]);
        u.y = bfp(-2.f * row[2], -2.f * row[3]);
        u.z = bfp(-2.f * row[4], -2.f * row[5]);
        u.w = bfp(-2.f * row[6], -2.f * row[7]);
        ((uint4*)ws)[gtid] = u;
    } else if (gtid < 4096) {                // G-plane frags (C^T)
        const int i = gtid - 2048;
        const int Mt = i >> 9, c = (i >> 7) & 3, h = (i >> 6) & 1;
        const int L = i & 63, m16 = L & 15, q = L >> 4;
        const float* base = centers + (size_t)(64 * c + 32 * h + 8 * q) * 64 + 16 * Mt + m16;
        uint4 u;
        u.x = bfp(base[0],   base[64]);
        u.y = bfp(base[128], base[192]);
        u.z = bfp(base[256], base[320]);
        u.w = bfp(base[384], base[448]);
        ((uint4*)ws)[gtid] = u;
    } else if (gtid < 4352) {                // cn2 / mu
        const int t = gtid - 4096;
        const float* r = centers + (size_t)t * 64;
        float a0 = 0.f, a1 = 0.f, a2 = 0.f, a3 = 0.f;
#pragma unroll
        for (int d = 0; d < 64; d += 4) {
            a0 = fmaf(r[d],     r[d],     a0);
            a1 = fmaf(r[d + 1], r[d + 1], a1);
            a2 = fmaf(r[d + 2], r[d + 2], a2);
            a3 = fmaf(r[d + 3], r[d + 3], a3);
        }
        float c2 = (a0 + a1) + (a2 + a3);
        ws[16384 + t] = ((__float_as_uint(c2) + 0x8000u) & 0xFFFF0000u) | bf1(mus[t]);
    }
}

__global__ __launch_bounds__(256, 1)
void pm_main(const float* __restrict__ z_in,
             const unsigned* __restrict__ ws,
             float* __restrict__ z_out) {
    __shared__ int4 sA[2048];          // 32 KB: S-plane frags, block-shared
    __shared__ int4 sWF[4][4][64];     // 16 KB: wave-private B-frag planes [wave][Kt*2+Nt][lane]

    const int4* wsA = (const int4*)ws;
    const int4* wsG = wsA + 2048;
    const unsigned* wsM = ws + 16384;

    const int tid  = threadIdx.x;
    const int lane = tid & 63;
    const int w    = tid >> 6;
    const int m16  = lane & 15;
    const int q    = lane >> 4;

    // copy S planes to LDS (lane-linear, coalesced, conflict-free)
#pragma unroll
    for (int i = 0; i < 8; ++i) sA[i * 256 + tid] = wsA[i * 256 + tid];
    __syncthreads();

    const int pbase = blockIdx.x * 128;   // 128 particles/block, 32/wave

    // z state in C/D layout: lane holds dims {16Mt+4q..+3} x particles {m16, m16+16}
    f32x4 z[4][2];
#pragma unroll
    for (int Mt = 0; Mt < 4; ++Mt)
#pragma unroll
        for (int Nt = 0; Nt < 2; ++Nt)
            z[Mt][Nt] = *(const f32x4*)(z_in + (size_t)(pbase + 32 * w + m16 + 16 * Nt) * 64
                                        + 16 * Mt + 4 * q);

    unsigned* wp = (unsigned*)&sWF[w][0][0];   // wave-private, 1024 uints

#pragma unroll 1
    for (int s = 0; s < STEPS; ++s) {
        // zz per particle (butterfly over q groups)
        float zzp[2];
#pragma unroll
        for (int Nt = 0; Nt < 2; ++Nt) {
            float a = 0.f;
#pragma unroll
            for (int Mt = 0; Mt < 4; ++Mt)
#pragma unroll
                for (int r = 0; r < 4; ++r) a = fmaf(z[Mt][Nt][r], z[Mt][Nt][r], a);
            a += __shfl_xor(a, 16, 64);
            a += __shfl_xor(a, 32, 64);
            zzp[Nt] = a;
        }

        // z (C/D regs) -> B-frag planes: scatter write
#pragma unroll
        for (int Mt = 0; Mt < 4; ++Mt) {
            const int Kt = Mt >> 1;
            const int qt = (2 * Mt + (q >> 1)) & 3;
#pragma unroll
            for (int Nt = 0; Nt < 2; ++Nt) {
                const int pos = ((Kt * 2 + Nt) * 64 + m16 + 16 * qt) * 4 + 2 * (q & 1);
                *(uint2*)(wp + pos) = make_uint2(bfp(z[Mt][Nt][0], z[Mt][Nt][1]),
                                                 bfp(z[Mt][Nt][2], z[Mt][Nt][3]));
            }
        }
        FragU zf[2][2];
#pragma unroll
        for (int Kt = 0; Kt < 2; ++Kt)
#pragma unroll
            for (int Nt = 0; Nt < 2; ++Nt)
                zf[Kt][Nt].i = sWF[w][Kt * 2 + Nt][lane];   // lane-linear read

        f32x4 g[4][2];
#pragma unroll
        for (int Mt = 0; Mt < 4; ++Mt)
#pragma unroll
            for (int Nt = 0; Nt < 2; ++Nt) g[Mt][Nt] = (f32x4){0.f, 0.f, 0.f, 0.f};
        float nacc[2] = {0.f, 0.f}, swp[2] = {0.f, 0.f};

#pragma unroll
        for (int c = 0; c < 4; ++c) {          // 4 chunks x 64 centers
            // S-phase, fused per Mt
#pragma unroll
            for (int Mt = 0; Mt < 4; ++Mt) {
                FragU a0, a1;
                a0.i = sA[((c * 4 + Mt) * 2 + 0) * 64 + lane];
                a1.i = sA[((c * 4 + Mt) * 2 + 1) * 64 + lane];
                f32x4 S[2];
#pragma unroll
                for (int Nt = 0; Nt < 2; ++Nt) {
                    f32x4 acc = (f32x4){0.f, 0.f, 0.f, 0.f};
                    acc = __builtin_amdgcn_mfma_f32_16x16x32_bf16(a0.h, zf[0][Nt].h, acc, 0, 0, 0);
                    acc = __builtin_amdgcn_mfma_f32_16x16x32_bf16(a1.h, zf[1][Nt].h, acc, 0, 0, 0);
                    S[Nt] = acc;   // S = -2*dot; row = center 64c+16Mt+4q+r, col = particle
                }

                const uint4 cmv = *(const uint4*)(wsM + 64 * c + 16 * Mt + 4 * q);
                float wv[2][4];
#pragma unroll
                for (int r = 0; r < 4; ++r) {
                    const unsigned cu = (r == 0) ? cmv.x : (r == 1) ? cmv.y
                                      : (r == 2) ? cmv.z : cmv.w;
                    const float cn2 = up_hi(cu), mu = up_lo(cu);
#pragma unroll
                    for (int Nt = 0; Nt < 2; ++Nt) {
                        float r2  = fmaxf(S[Nt][r] + (zzp[Nt] + cn2), 0.f) + EPSF;
                        float rin = __builtin_amdgcn_rsqf(r2);
                        float mur = mu * rin;
                        nacc[Nt] += mur;
                        float wval = mur * rin * rin;   // mu / r^3
                        swp[Nt] += wval;
                        wv[Nt][r] = wval;
                    }
                }
                const int Kt = Mt >> 1;
                const int qt = (2 * Mt + (q >> 1)) & 3;
#pragma unroll
                for (int Nt = 0; Nt < 2; ++Nt) {
                    const int pos = ((Kt * 2 + Nt) * 64 + m16 + 16 * qt) * 4 + 2 * (q & 1);
                    *(uint2*)(wp + pos) = make_uint2(bfpt(wv[Nt][0], wv[Nt][1]),
                                                     bfpt(wv[Nt][2], wv[Nt][3]));
                }
            }

            // G-phase: wf frags (lane-linear) + global ga frags (L2)
            FragU wf[2][2];
#pragma unroll
            for (int Kt = 0; Kt < 2; ++Kt)
#pragma unroll
                for (int Nt = 0; Nt < 2; ++Nt)
                    wf[Kt][Nt].i = sWF[w][Kt * 2 + Nt][lane];
#pragma unroll
            for (int Mt = 0; Mt < 4; ++Mt) {
                FragU ga0, ga1;
                ga0.i = wsG[((Mt * 4 + c) * 2 + 0) * 64 + lane];
                ga1.i = wsG[((Mt * 4 + c) * 2 + 1) * 64 + lane];
#pragma unroll
                for (int Nt = 0; Nt < 2; ++Nt) {
                    g[Mt][Nt] = __builtin_amdgcn_mfma_f32_16x16x32_bf16(ga0.h, wf[0][Nt].h, g[Mt][Nt], 0, 0, 0);
                    g[Mt][Nt] = __builtin_amdgcn_mfma_f32_16x16x32_bf16(ga1.h, wf[1][Nt].h, g[Mt][Nt], 0, 0, 0);
                }
            }
        }

        // reduce n, sw across q groups; update z
        float tco[2], swf[2];
#pragma unroll
        for (int Nt = 0; Nt < 2; ++Nt) {
            float a = nacc[Nt];
            a += __shfl_xor(a, 16, 64);
            a += __shfl_xor(a, 32, 64);
            float b = swp[Nt];
            b += __shfl_xor(b, 16, 64);
            b += __shfl_xor(b, 32, 64);
            tco[Nt] = DTB * __builtin_amdgcn_rcpf(1.f + a);
            swf[Nt] = b;
        }
#pragma unroll
        for (int Mt = 0; Mt < 4; ++Mt)
#pragma unroll
            for (int Nt = 0; Nt < 2; ++Nt)
#pragma unroll
                for (int r = 0; r < 4; ++r) {
                    float gd = fmaf(-swf[Nt], z[Mt][Nt][r], g[Mt][Nt][r]);
                    z[Mt][Nt][r] = med3(fmaf(tco[Nt], gd, z[Mt][Nt][r]), -3.f, 3.f);
                }
    }

    // direct C/D-layout store (16B segments, rows covered across lanes)
#pragma unroll
    for (int Mt = 0; Mt < 4; ++Mt)
#pragma unroll
        for (int Nt = 0; Nt < 2; ++Nt)
            *(f32x4*)(z_out + (size_t)(pbase + 32 * w + m16 + 16 * Nt) * 64
                      + 16 * Mt + 4 * q) = z[Mt][Nt];
}

extern "C" void kernel_launch(void* const* d_in, const int* in_sizes, int n_in,
                              void* d_out, int out_size, void* d_ws, size_t ws_size,
                              hipStream_t stream) {
    const float* z       = (const float*)d_in[0];
    const float* centers = (const float*)d_in[1];
    const float* mus     = (const float*)d_in[2];
    float* out           = (float*)d_out;
    unsigned* ws         = (unsigned*)d_ws;

    pm_prep<<<dim3(17), dim3(256), 0, stream>>>(centers, mus, ws);
    // 131072 particles / 128 per block (4 waves x 32) = 1024 blocks
    pm_main<<<dim3(1024), dim3(256), 0, stream>>>(z, ws, out);
}